// Round 1
// baseline (7480.681 us; speedup 1.0000x reference)
//
#include <hip/hip_runtime.h>
#include <math.h>

// ============================================================================
// CrossAttention_Mirror: fp32 correctness baseline.
// Pipeline: conv1x1(+b) x2 -> cross flash-attn -> conv3x3+BN+ReLU -> cat(flow)
//           -> self flash-attn (C padded 258->320) -> conv3x3+BN+ReLU -> pred.
// ws layout: 5 slots of 4*320*4096 f32 (21MB) + stats + transformed conv wts.
// ============================================================================

#define NPIX 4096   // H*W = 64*64
#define NB   4

// ---------------- 1x1 conv as GEMM: Y[b,o,n] = sum_i W[o,i] X[b,i,n] (+bias)
// block 256 (16x16), tile 128x128, K-chunk 32, per-thread 8x8
__global__ __launch_bounds__(256) void gemm1x1_kernel(
    const float* __restrict__ X, const float* __restrict__ W,
    const float* __restrict__ Bias, float* __restrict__ Y,
    int I, int Ireal, int O, int Oreal, int N)
{
  const int b  = blockIdx.z;
  const int n0 = blockIdx.x * 128;
  const int o0 = blockIdx.y * 128;
  const int tid = threadIdx.x;
  const int tx = tid & 15, ty = tid >> 4;
  const float* Xb = X + (size_t)b * I * N;
  float*       Yb = Y + (size_t)b * O * N;

  __shared__ float As[32][130];  // [k][o] (+2 pad: 2-way is free)
  __shared__ float Bs[32][129];  // [k][n]

  float acc[8][8];
#pragma unroll
  for (int u = 0; u < 8; ++u)
#pragma unroll
    for (int v = 0; v < 8; ++v) acc[u][v] = 0.f;

  const int nchunk = (Ireal + 31) >> 5;
  for (int ch = 0; ch < nchunk; ++ch) {
    const int k0 = ch << 5;
    __syncthreads();
#pragma unroll
    for (int r = 0; r < 16; ++r) {           // 32x128 weights
      int e  = tid + r * 256;
      int kk = e & 31, oo = e >> 5;
      int i = k0 + kk, o = o0 + oo;
      As[kk][oo] = (i < Ireal && o < Oreal) ? W[(size_t)o * Ireal + i] : 0.f;
    }
#pragma unroll
    for (int r = 0; r < 16; ++r) {           // 32x128 activations
      int e  = tid + r * 256;
      int nn = e & 127, kk = e >> 7;
      int i = k0 + kk;
      Bs[kk][nn] = (i < I) ? Xb[(size_t)i * N + n0 + nn] : 0.f;
    }
    __syncthreads();
#pragma unroll 4
    for (int kk = 0; kk < 32; ++kk) {
      float a[8], bb[8];
#pragma unroll
      for (int u = 0; u < 8; ++u) a[u] = As[kk][ty + 16 * u];
#pragma unroll
      for (int v = 0; v < 8; ++v) bb[v] = Bs[kk][tx + 16 * v];
#pragma unroll
      for (int u = 0; u < 8; ++u)
#pragma unroll
        for (int v = 0; v < 8; ++v) acc[u][v] = fmaf(a[u], bb[v], acc[u][v]);
    }
  }
#pragma unroll
  for (int u = 0; u < 8; ++u) {
    int o = o0 + ty + 16 * u;
    if (o < O) {
      float bia = (Bias != nullptr && o < Oreal) ? Bias[o] : 0.f;
#pragma unroll
      for (int v = 0; v < 8; ++v)
        Yb[(size_t)o * N + n0 + tx + 16 * v] = acc[u][v] + bia;
    }
  }
}

// ---------------- flash attention (no 1/sqrt(d)), fp32, online softmax.
// Q,K,V,R,Out: [B][C][N].  Out = gamma * (V @ softmax(Q^T K)^T) + R.
// Out may alias Q (each block writes only its own n-columns, after last Q read).
// block 256 (16x16): n-tile 32 (rows ty+16u, u<2), m-tile 64 (cols tx+16v).
template<int C>
__global__ __launch_bounds__(256) void flash_kernel(
    const float* __restrict__ Q, const float* __restrict__ K,
    const float* __restrict__ V, const float* __restrict__ R,
    float* __restrict__ Out, const float* __restrict__ gamma_p, int N)
{
  constexpr int CW  = C / 16;   // acc channels per thread
  constexpr int NCH = C / 64;   // channel chunks
  const int b  = blockIdx.y;
  const int n0 = blockIdx.x * 32;
  const int tid = threadIdx.x;
  const int tx = tid & 15, ty = tid >> 4;
  const size_t base = (size_t)b * C * N;
  const float* Qb = Q + base;
  const float* Kb = K + base;
  const float* Vb = V + base;
  const float* Rb = R + base;
  float*       Ob = Out + base;

  __shared__ float Qs[64][33];  // [c-chunk][n]
  __shared__ float Ks[64][65];  // [c-chunk][m]
  __shared__ float Ps[32][65];  // [n][m]
  __shared__ float Vs[64][65];  // [c-chunk][m]

  float acc[2][CW];
#pragma unroll
  for (int u = 0; u < 2; ++u)
#pragma unroll
    for (int w = 0; w < CW; ++w) acc[u][w] = 0.f;
  float mrun[2], lrun[2];
#pragma unroll
  for (int u = 0; u < 2; ++u) { mrun[u] = -INFINITY; lrun[u] = 0.f; }

  for (int m0 = 0; m0 < N; m0 += 64) {
    // ----- S = Q^T K for this tile
    float s[2][4];
#pragma unroll
    for (int u = 0; u < 2; ++u)
#pragma unroll
      for (int v = 0; v < 4; ++v) s[u][v] = 0.f;
#pragma unroll
    for (int ch = 0; ch < NCH; ++ch) {
      const int c0 = ch * 64;
      __syncthreads();
      for (int e = tid; e < 2048; e += 256) {      // Q chunk [64c][32n]
        int cc = e >> 5, nn = e & 31;
        Qs[cc][nn] = Qb[(size_t)(c0 + cc) * N + n0 + nn];
      }
      for (int e = tid; e < 4096; e += 256) {      // K chunk [64c][64m]
        int cc = e >> 6, mm = e & 63;
        Ks[cc][mm] = Kb[(size_t)(c0 + cc) * N + m0 + mm];
      }
      __syncthreads();
#pragma unroll 4
      for (int kk = 0; kk < 64; ++kk) {
        float a[2], bb[4];
#pragma unroll
        for (int u = 0; u < 2; ++u) a[u] = Qs[kk][ty + 16 * u];
#pragma unroll
        for (int v = 0; v < 4; ++v) bb[v] = Ks[kk][tx + 16 * v];
#pragma unroll
        for (int u = 0; u < 2; ++u)
#pragma unroll
          for (int v = 0; v < 4; ++v) s[u][v] = fmaf(a[u], bb[v], s[u][v]);
      }
    }
    // ----- online softmax over m (rows = 16 consecutive lanes, shfl reduce)
#pragma unroll
    for (int u = 0; u < 2; ++u) {
      float pm = fmaxf(fmaxf(s[u][0], s[u][1]), fmaxf(s[u][2], s[u][3]));
#pragma unroll
      for (int off = 1; off < 16; off <<= 1) pm = fmaxf(pm, __shfl_xor(pm, off));
      float mnew = fmaxf(mrun[u], pm);
      float scal = __expf(mrun[u] - mnew);
      mrun[u] = mnew;
      float rs = 0.f;
#pragma unroll
      for (int v = 0; v < 4; ++v) { s[u][v] = __expf(s[u][v] - mnew); rs += s[u][v]; }
#pragma unroll
      for (int off = 1; off < 16; off <<= 1) rs += __shfl_xor(rs, off);
      lrun[u] = lrun[u] * scal + rs;
#pragma unroll
      for (int w = 0; w < CW; ++w) acc[u][w] *= scal;
    }
    __syncthreads();                 // prev-tile PV reads of Ps done
#pragma unroll
    for (int u = 0; u < 2; ++u)
#pragma unroll
      for (int v = 0; v < 4; ++v) Ps[ty + 16 * u][tx + 16 * v] = s[u][v];
    __syncthreads();
    // ----- O += P V^T  (per c-chunk)
#pragma unroll
    for (int ch = 0; ch < NCH; ++ch) {
      const int c0 = ch * 64;
      __syncthreads();
      for (int e = tid; e < 4096; e += 256) {
        int cc = e >> 6, mm = e & 63;
        Vs[cc][mm] = Vb[(size_t)(c0 + cc) * N + m0 + mm];
      }
      __syncthreads();
#pragma unroll 4
      for (int mm = 0; mm < 64; ++mm) {
        float pr[2], vv[4];
#pragma unroll
        for (int u = 0; u < 2; ++u) pr[u] = Ps[ty + 16 * u][mm];
#pragma unroll
        for (int w4 = 0; w4 < 4; ++w4) vv[w4] = Vs[tx + 16 * w4][mm];
#pragma unroll
        for (int u = 0; u < 2; ++u)
#pragma unroll
          for (int w4 = 0; w4 < 4; ++w4)
            acc[u][ch * 4 + w4] = fmaf(pr[u], vv[w4], acc[u][ch * 4 + w4]);
      }
    }
  }
  // ----- epilogue: gamma * O/l + residual
  const float g = *gamma_p;
#pragma unroll
  for (int u = 0; u < 2; ++u) {
    const float rinv = 1.f / lrun[u];
    const int n = n0 + ty + 16 * u;
#pragma unroll
    for (int w = 0; w < CW; ++w) {
      const int c = (w >> 2) * 64 + 16 * (w & 3) + tx;
      Ob[(size_t)c * N + n] = g * acc[u][w] * rinv + Rb[(size_t)c * N + n];
    }
  }
}

// ---------------- weight transform [O][I][3][3] -> [3][3][I][O] (coalesced A reads)
__global__ void wtrans_kernel(const float* __restrict__ Win, float* __restrict__ Wout,
                              int O, int I)
{
  size_t total = (size_t)O * I * 9;
  for (size_t e = (size_t)blockIdx.x * 256 + threadIdx.x; e < total;
       e += (size_t)gridDim.x * 256) {
    int o = (int)(e % O);
    size_t r = e / O;
    int i = (int)(r % I);
    int t = (int)(r / I);            // t = dy*3+dx
    Wout[e] = Win[((size_t)o * I + i) * 9 + t];
  }
}

// ---------------- conv3x3 SAME: Y[b,o,h,w] = sum_{i,dy,dx} W2[dy][dx][i][o] X[b,i,h+dy-1,w+dx-1]
// block 256 (16x16): o-tile 128 (rows ty+16u, u<8), one image row (w = tx+16v, v<4)
__global__ __launch_bounds__(256) void conv3x3_kernel(
    const float* __restrict__ X, const float* __restrict__ W2,
    float* __restrict__ Y, int Cin, int Ireal, int O, int N)
{
  const int b  = blockIdx.z;
  const int h  = blockIdx.x;
  const int o0 = blockIdx.y * 128;
  const int tid = threadIdx.x;
  const int tx = tid & 15, ty = tid >> 4;
  const float* Xb = X + (size_t)b * Cin * N;
  float*       Yb = Y + (size_t)b * O * N;

  __shared__ float As[3][32][130];   // [dx][k][o]
  __shared__ float Xs[32][64];       // [k][w]

  float acc[8][4];
#pragma unroll
  for (int u = 0; u < 8; ++u)
#pragma unroll
    for (int v = 0; v < 4; ++v) acc[u][v] = 0.f;

  const int nchunk = (Ireal + 31) >> 5;
  for (int ch = 0; ch < nchunk; ++ch) {
    const int c0 = ch << 5;
    for (int dy = 0; dy < 3; ++dy) {
      const int hs = h + dy - 1;
      const bool hv = (hs >= 0) && (hs < 64);
      __syncthreads();
      for (int e = tid; e < 2048; e += 256) {        // X row chunk
        int kk = e >> 6, w = e & 63;
        float val = 0.f;
        if (hv) val = Xb[(size_t)(c0 + kk) * N + hs * 64 + w];
        Xs[kk][w] = val;
      }
      for (int e = tid; e < 12288; e += 256) {       // 3 dx-planes of weights
        int oo = e & 127;
        int kd = e >> 7;
        int kk = kd & 31, dx = kd >> 5;
        int i = c0 + kk;
        As[dx][kk][oo] = (i < Ireal)
            ? W2[((size_t)(dy * 3 + dx) * Ireal + i) * O + o0 + oo] : 0.f;
      }
      __syncthreads();
#pragma unroll
      for (int dx = 0; dx < 3; ++dx) {
#pragma unroll 4
        for (int kk = 0; kk < 32; ++kk) {
          float a[8], bb[4];
#pragma unroll
          for (int u = 0; u < 8; ++u) a[u] = As[dx][kk][ty + 16 * u];
#pragma unroll
          for (int v = 0; v < 4; ++v) {
            int wi = tx + 16 * v + dx - 1;
            bb[v] = (wi >= 0 && wi < 64) ? Xs[kk][wi] : 0.f;
          }
#pragma unroll
          for (int u = 0; u < 8; ++u)
#pragma unroll
            for (int v = 0; v < 4; ++v) acc[u][v] = fmaf(a[u], bb[v], acc[u][v]);
        }
      }
    }
  }
#pragma unroll
  for (int u = 0; u < 8; ++u) {
    int o = o0 + ty + 16 * u;
#pragma unroll
    for (int v = 0; v < 4; ++v)
      Yb[(size_t)o * N + h * 64 + tx + 16 * v] = acc[u][v];
  }
}

// ---------------- BN stats (biased var over B,H,W), one block per channel
__global__ __launch_bounds__(256) void bn_stats_kernel(
    const float* __restrict__ X, float* __restrict__ Mean, float* __restrict__ Rstd,
    int Cstride, int N)
{
  const int c = blockIdx.x;
  float s = 0.f, sq = 0.f;
  for (int b = 0; b < NB; ++b) {
    const float* p = X + ((size_t)b * Cstride + c) * N;
    for (int n = threadIdx.x; n < N; n += 256) {
      float v = p[n];
      s += v; sq += v * v;
    }
  }
  __shared__ float rs[256], rq[256];
  rs[threadIdx.x] = s; rq[threadIdx.x] = sq;
  __syncthreads();
  for (int st = 128; st > 0; st >>= 1) {
    if (threadIdx.x < st) { rs[threadIdx.x] += rs[threadIdx.x + st];
                            rq[threadIdx.x] += rq[threadIdx.x + st]; }
    __syncthreads();
  }
  if (threadIdx.x == 0) {
    const float inv = 1.f / (float)(NB * N);
    float mean = rs[0] * inv;
    float var  = rq[0] * inv - mean * mean;
    Mean[c] = mean;
    Rstd[c] = 1.f / sqrtf(var + 1e-5f);
  }
}

// ---------------- BN apply + ReLU (+ optional flow concat + zero-pad channels)
__global__ __launch_bounds__(256) void bn_apply_kernel(
    const float* __restrict__ X, const float* __restrict__ Flow,
    const float* __restrict__ Mean, const float* __restrict__ Rstd,
    const float* __restrict__ Gm, const float* __restrict__ Bt,
    float* __restrict__ Y, int Cy, int N, int hasflow)
{
  size_t idx = (size_t)blockIdx.x * 256 + threadIdx.x;
  size_t total = (size_t)NB * Cy * N;
  if (idx >= total) return;
  int n = (int)(idx & (N - 1));
  size_t r = idx >> 12;               // N == 4096
  int c = (int)(r % Cy);
  int b = (int)(r / Cy);
  float val;
  if (c < 256) {
    float x = X[((size_t)b * 256 + c) * N + n];
    float xn = (x - Mean[c]) * Rstd[c];
    val = fmaxf(xn * Gm[c] + Bt[c], 0.f);
  } else if (hasflow && c < 258) {
    val = Flow[((size_t)b * 2 + (c - 256)) * N + n];
  } else {
    val = 0.f;
  }
  Y[idx] = val;
}

// ---------------- pred: out[b,n] = sum_c W[c] X[b,c,n] + bias
__global__ __launch_bounds__(256) void pred_kernel(
    const float* __restrict__ X, const float* __restrict__ W,
    const float* __restrict__ Bias, float* __restrict__ Out, int C, int N)
{
  int b = blockIdx.y;
  int n = blockIdx.x * 256 + threadIdx.x;
  const float* Xb = X + (size_t)b * C * N;
  float acc = 0.f;
  for (int c = 0; c < 256; ++c) acc = fmaf(W[c], Xb[(size_t)c * N + n], acc);
  Out[(size_t)b * N + n] = acc + Bias[0];
}

// ============================================================================
extern "C" void kernel_launch(void* const* d_in, const int* in_sizes, int n_in,
                              void* d_out, int out_size, void* d_ws, size_t ws_size,
                              hipStream_t stream)
{
  (void)in_sizes; (void)n_in; (void)out_size; (void)ws_size;
  const float* x      = (const float*)d_in[0];
  const float* y      = (const float*)d_in[1];
  const float* flow   = (const float*)d_in[2];
  const float* w1x1   = (const float*)d_in[3];
  const float* b1x1   = (const float*)d_in[4];
  const float* ca_wq  = (const float*)d_in[5];
  const float* ca_wk  = (const float*)d_in[6];
  const float* ca_wv  = (const float*)d_in[7];
  const float* ca_g   = (const float*)d_in[8];
  const float* cbr1_w = (const float*)d_in[9];
  const float* bn1_g  = (const float*)d_in[10];
  const float* bn1_b  = (const float*)d_in[11];
  const float* sa_wq  = (const float*)d_in[12];
  const float* sa_wk  = (const float*)d_in[13];
  const float* sa_wv  = (const float*)d_in[14];
  const float* sa_g   = (const float*)d_in[15];
  const float* cbr2_w = (const float*)d_in[16];
  const float* bn2_g  = (const float*)d_in[17];
  const float* bn2_b  = (const float*)d_in[18];
  const float* pred_w = (const float*)d_in[19];
  const float* pred_b = (const float*)d_in[20];
  float* out = (float*)d_out;

  const int N = NPIX;
  const size_t SLOT = (size_t)NB * 320 * NPIX;   // 5,242,880 floats
  float* ws = (float*)d_ws;
  float* A  = ws + 0 * SLOT;   // xb -> conv1 raw -> conv2 raw
  float* Bf = ws + 1 * SLOT;   // yb -> flash1 out(t) ... cat
  float* Cc = ws + 2 * SLOT;   // q -> t (flash1 out aliases q) -> q2 -> t2
  float* D  = ws + 3 * SLOT;   // k -> k2 -> bn2 out
  float* E  = ws + 4 * SLOT;   // v -> v2
  float* mean1 = ws + 5 * SLOT;
  float* rstd1 = mean1 + 256;
  float* w2a   = rstd1 + 256;              // conv1 wts [3][3][256][256]
  float* w2b   = w2a + (size_t)9 * 256 * 256;  // conv2 wts [3][3][258][256]

  dim3 blk(256);

  // conv weight transforms (independent of activations)
  wtrans_kernel<<<dim3(512), blk, 0, stream>>>(cbr1_w, w2a, 256, 256);
  wtrans_kernel<<<dim3(512), blk, 0, stream>>>(cbr2_w, w2b, 256, 258);

  // xb = W1 x + b1 ; yb = W1 y + b1
  gemm1x1_kernel<<<dim3(32, 2, 4), blk, 0, stream>>>(x, w1x1, b1x1, A, 512, 512, 256, 256, N);
  gemm1x1_kernel<<<dim3(32, 2, 4), blk, 0, stream>>>(y, w1x1, b1x1, Bf, 512, 512, 256, 256, N);

  // q,k,v (no bias)
  gemm1x1_kernel<<<dim3(32, 2, 4), blk, 0, stream>>>(A,  ca_wq, nullptr, Cc, 256, 256, 256, 256, N);
  gemm1x1_kernel<<<dim3(32, 2, 4), blk, 0, stream>>>(Bf, ca_wk, nullptr, D,  256, 256, 256, 256, N);
  gemm1x1_kernel<<<dim3(32, 2, 4), blk, 0, stream>>>(Bf, ca_wv, nullptr, E,  256, 256, 256, 256, N);

  // cross-attn: t = gamma * attn(q,k,v) + xb   (out aliases q)
  flash_kernel<256><<<dim3(128, 4), blk, 0, stream>>>(Cc, D, E, A, Cc, ca_g, N);

  // conv3x3 + BN + ReLU -> cat with flow into 320-ch (zeros beyond 258)
  conv3x3_kernel<<<dim3(64, 2, 4), blk, 0, stream>>>(Cc, w2a, A, 256, 256, 256, N);
  bn_stats_kernel<<<dim3(256), blk, 0, stream>>>(A, mean1, rstd1, 256, N);
  bn_apply_kernel<<<dim3(20480), blk, 0, stream>>>(A, flow, mean1, rstd1, bn1_g, bn1_b,
                                                   Bf, 320, N, 1);

  // self-attn qkv (padded O=320, real 258)
  gemm1x1_kernel<<<dim3(32, 3, 4), blk, 0, stream>>>(Bf, sa_wq, nullptr, Cc, 320, 258, 320, 258, N);
  gemm1x1_kernel<<<dim3(32, 3, 4), blk, 0, stream>>>(Bf, sa_wk, nullptr, D,  320, 258, 320, 258, N);
  gemm1x1_kernel<<<dim3(32, 3, 4), blk, 0, stream>>>(Bf, sa_wv, nullptr, E,  320, 258, 320, 258, N);

  // self-attn: t2 = gamma * attn + cat   (out aliases q2; pad channels stay 0)
  flash_kernel<320><<<dim3(128, 4), blk, 0, stream>>>(Cc, D, E, Bf, Cc, sa_g, N);

  // conv3x3 #2 + BN + ReLU
  conv3x3_kernel<<<dim3(64, 2, 4), blk, 0, stream>>>(Cc, w2b, A, 320, 258, 256, N);
  bn_stats_kernel<<<dim3(256), blk, 0, stream>>>(A, mean1, rstd1, 256, N);
  bn_apply_kernel<<<dim3(16384), blk, 0, stream>>>(A, nullptr, mean1, rstd1, bn2_g, bn2_b,
                                                   D, 256, N, 0);

  // pred 1x1 (O=1)
  pred_kernel<<<dim3(16, 4), blk, 0, stream>>>(D, pred_w, pred_b, out, 256, N);
}